// Round 2
// baseline (324.050 us; speedup 1.0000x reference)
//
#include <hip/hip_runtime.h>

typedef __attribute__((ext_vector_type(4))) float          f32x4;
typedef __attribute__((ext_vector_type(8))) __bf16         bf16x8;
typedef __attribute__((ext_vector_type(8))) unsigned short u16x8;

#define B_  1024
#define D_  2048
#define H_  2048
#define K_  4096   /* D + H  */
#define N_  8192   /* 4 * H  */

// ---------- helpers ----------
__device__ __forceinline__ unsigned short f2bf_rne(float f) {
  unsigned u = __builtin_bit_cast(unsigned, f);
  u += 0x7fffu + ((u >> 16) & 1u);           // round-to-nearest-even
  return (unsigned short)(u >> 16);
}

__device__ __forceinline__ float sigf(float x) {
  return 1.f / (1.f + __expf(-x));
}
__device__ __forceinline__ float tanhf_(float x) {
  float ax = fabsf(x);
  float t  = __expf(-2.f * ax);              // in (0,1], no overflow
  float r  = (1.f - t) / (1.f + t);
  return (x < 0.f) ? -r : r;
}

typedef const __attribute__((address_space(1))) unsigned int* gptr_t;
typedef __attribute__((address_space(3))) unsigned int*       lptr_t;
__device__ __forceinline__ void gl_lds16(const void* g, void* l) {
  __builtin_amdgcn_global_load_lds((gptr_t)g, (lptr_t)l, 16, 0, 0);
}

// ---------- kernel 1: convert [x | h] -> bf16 merged (1024 x 4096) ----------
__global__ __launch_bounds__(256) void k_convert_merged(
    const float* __restrict__ x, const float* __restrict__ h,
    unsigned short* __restrict__ merged) {
  int tid = blockIdx.x * 256 + threadIdx.x;   // 0 .. 524287
  int e0  = tid * 8;                          // element offset in merged
  int b   = e0 >> 12;                         // / 4096
  int col = e0 & 4095;
  const float* src = (col < D_) ? (x + (size_t)b * D_ + col)
                                : (h + (size_t)b * H_ + (col - D_));
  f32x4 v0 = *(const f32x4*)src;
  f32x4 v1 = *(const f32x4*)(src + 4);
  u16x8 o;
  o[0] = f2bf_rne(v0[0]); o[1] = f2bf_rne(v0[1]);
  o[2] = f2bf_rne(v0[2]); o[3] = f2bf_rne(v0[3]);
  o[4] = f2bf_rne(v1[0]); o[5] = f2bf_rne(v1[1]);
  o[6] = f2bf_rne(v1[2]); o[7] = f2bf_rne(v1[3]);
  *(u16x8*)(merged + e0) = o;
}

// ---------- kernel 2: W (4096 x 8192 f32, KxN) -> Wt (8192 x 4096 bf16, NxK) --
__global__ __launch_bounds__(256) void k_transpose_w(
    const float* __restrict__ W, unsigned short* __restrict__ Wt) {
  __shared__ unsigned short lt[64][72];       // +8 pad: rows 16B-aligned, banks spread
  int t  = threadIdx.x;
  int n0 = blockIdx.x * 64;                   // N tile (8192/64 = 128)
  int k0 = blockIdx.y * 64;                   // K tile (4096/64 = 64)
  int rr = t >> 4;                            // 0..15
  int cc = (t & 15) * 4;                      // 0..60
#pragma unroll
  for (int i = 0; i < 4; ++i) {
    int row = rr + i * 16;                    // k-row within tile
    f32x4 v = *(const f32x4*)&W[(size_t)(k0 + row) * N_ + n0 + cc];
#pragma unroll
    for (int j = 0; j < 4; ++j) lt[cc + j][row] = f2bf_rne(v[j]);
  }
  __syncthreads();
  int wr  = t >> 2;                           // 0..63 : n-row within tile
  int seg = (t & 3) * 16;                     // 0,16,32,48
  u16x8 a = *(const u16x8*)&lt[wr][seg];
  u16x8 b = *(const u16x8*)&lt[wr][seg + 8];
  unsigned short* dst = &Wt[(size_t)(n0 + wr) * K_ + k0 + seg];
  *(u16x8*)dst       = a;
  *(u16x8*)(dst + 8) = b;
}

// ---------- kernel 3: GEMM  C(1024x8192 f32) = merged(1024x4096) * Wt^T ------
// m97 structure: 128x128 tile, BK=64, 4 waves (2x2), 16x16x32 bf16 MFMA,
// global_load_lds width=16 staging, linear LDS.
#define TM 128
#define TN 128
#define TK 64

__global__ __launch_bounds__(256) void k_gemm(
    const unsigned short* __restrict__ A,   // M x K bf16 row-major
    const unsigned short* __restrict__ Bt,  // N x K bf16 row-major
    float* __restrict__ C) {                // M x N f32
  __shared__ unsigned short As[TM * TK];    // [128][64], row stride 128 B
  __shared__ unsigned short Bs[TN * TK];
  const int t    = threadIdx.x;
  const int bx   = blockIdx.x;              // N tile: 0..63
  const int by   = blockIdx.y;              // M tile: 0..7
  const int wid  = t >> 6;
  const int lane = t & 63;
  const int wr   = wid >> 1, wc = wid & 1;  // 2x2 waves, 64x64 each
  const int ln15 = lane & 15, kq = lane >> 4;

  const int srow  = t >> 3;                 // 0..31 per sweep
  const int scolb = (t & 7) * 16;           // byte col within 128-B row

  const char* gA = (const char*)A + (size_t)(by * TM + srow) * (K_ * 2) + scolb;
  const char* gB = (const char*)Bt + (size_t)(bx * TN + srow) * (K_ * 2) + scolb;
  char* lA = (char*)As + srow * (TK * 2) + scolb;
  char* lB = (char*)Bs + srow * (TK * 2) + scolb;

  f32x4 acc[4][4] = {};

  for (int kt = 0; kt < K_ / TK; ++kt) {
    const int gofs = kt * (TK * 2);         // byte offset along K
#pragma unroll
    for (int i = 0; i < 4; ++i) {           // 32 rows per sweep
      gl_lds16(gA + (size_t)(i * 32) * (K_ * 2) + gofs, lA + i * 32 * (TK * 2));
      gl_lds16(gB + (size_t)(i * 32) * (K_ * 2) + gofs, lB + i * 32 * (TK * 2));
    }
    __syncthreads();                        // compiler drains vmcnt before barrier
#pragma unroll
    for (int ks = 0; ks < 2; ++ks) {        // two K=32 sub-steps
      bf16x8 a[4], b[4];
#pragma unroll
      for (int mi = 0; mi < 4; ++mi)
        a[mi] = *(const bf16x8*)((const char*)As +
                 (wr * 64 + mi * 16 + ln15) * (TK * 2) + ks * 64 + kq * 16);
#pragma unroll
      for (int ni = 0; ni < 4; ++ni)
        b[ni] = *(const bf16x8*)((const char*)Bs +
                 (wc * 64 + ni * 16 + ln15) * (TK * 2) + ks * 64 + kq * 16);
#pragma unroll
      for (int mi = 0; mi < 4; ++mi)
#pragma unroll
        for (int ni = 0; ni < 4; ++ni)
          acc[mi][ni] = __builtin_amdgcn_mfma_f32_16x16x32_bf16(
              a[mi], b[ni], acc[mi][ni], 0, 0, 0);
    }
    __syncthreads();
  }

  // epilogue: C/D layout col = lane&15, row = (lane>>4)*4 + reg  [m89/m91]
  const int crow0 = by * TM + wr * 64 + kq * 4;
  const int ccol0 = bx * TN + wc * 64 + ln15;
#pragma unroll
  for (int mi = 0; mi < 4; ++mi)
#pragma unroll
    for (int ni = 0; ni < 4; ++ni)
#pragma unroll
      for (int r = 0; r < 4; ++r)
        C[(size_t)(crow0 + mi * 16 + r) * N_ + ccol0 + ni * 16] = acc[mi][ni][r];
}

// ---------- kernel 4: LSTM gates ----------
__global__ __launch_bounds__(256) void k_gates(
    const float* __restrict__ wsum, const float* __restrict__ c,
    float* __restrict__ out) {
  int tid = blockIdx.x * 256 + threadIdx.x;  // 0 .. 524287
  int b   = tid >> 9;                        // / 512 float4-per-row
  int j   = (tid & 511) * 4;
  const float* base = wsum + (size_t)b * N_;
  f32x4 f  = *(const f32x4*)(base + j);
  f32x4 ii = *(const f32x4*)(base + H_ + j);
  f32x4 g  = *(const f32x4*)(base + 2 * H_ + j);
  f32x4 o  = *(const f32x4*)(base + 3 * H_ + j);
  f32x4 cc = *(const f32x4*)&c[(size_t)b * H_ + j];
  f32x4 r;
#pragma unroll
  for (int q = 0; q < 4; ++q) {
    float cn = cc[q] * sigf(f[q]) + sigf(ii[q]) * tanhf_(g[q]);
    r[q] = sigf(o[q]) * tanhf_(cn);
  }
  *(f32x4*)&out[(size_t)b * H_ + j] = r;
}

// ---------- launch ----------
extern "C" void kernel_launch(void* const* d_in, const int* in_sizes, int n_in,
                              void* d_out, int out_size, void* d_ws, size_t ws_size,
                              hipStream_t stream) {
  (void)in_sizes; (void)n_in; (void)out_size; (void)ws_size;
  const float* x = (const float*)d_in[0];
  const float* h = (const float*)d_in[1];
  const float* c = (const float*)d_in[2];
  const float* W = (const float*)d_in[3];
  float* out = (float*)d_out;

  char* ws = (char*)d_ws;
  unsigned short* merged = (unsigned short*)ws;                              // 8 MB
  unsigned short* Wt     = (unsigned short*)(ws + (size_t)8  * 1024 * 1024); // 64 MB
  float*          wsum   = (float*)(ws + (size_t)72 * 1024 * 1024);          // 32 MB

  k_convert_merged<<<2048, 256, 0, stream>>>(x, h, merged);
  k_transpose_w<<<dim3(128, 64), 256, 0, stream>>>(W, Wt);
  k_gemm<<<dim3(N_ / TN, B_ / TM), 256, 0, stream>>>(merged, Wt, wsum);
  k_gates<<<2048, 256, 0, stream>>>(wsum, c, out);
}

// Round 3
// 322.451 us; speedup vs baseline: 1.0050x; 1.0050x over previous
//
#include <hip/hip_runtime.h>

typedef __attribute__((ext_vector_type(4))) float          f32x4;
typedef __attribute__((ext_vector_type(8))) __bf16         bf16x8;
typedef __attribute__((ext_vector_type(8))) unsigned short u16x8;

#define B_  1024
#define D_  2048
#define H_  2048
#define K_  4096   /* D + H  */
#define N_  8192   /* 4 * H  */

// ---------- helpers ----------
__device__ __forceinline__ unsigned short f2bf_rne(float f) {
  unsigned u = __builtin_bit_cast(unsigned, f);
  u += 0x7fffu + ((u >> 16) & 1u);           // round-to-nearest-even
  return (unsigned short)(u >> 16);
}

__device__ __forceinline__ float sigf(float x) {
  return 1.f / (1.f + __expf(-x));
}
__device__ __forceinline__ float tanhf_(float x) {
  float ax = fabsf(x);
  float t  = __expf(-2.f * ax);              // in (0,1], no overflow
  float r  = (1.f - t) / (1.f + t);
  return (x < 0.f) ? -r : r;
}

typedef const __attribute__((address_space(1))) unsigned int* gptr_t;
typedef __attribute__((address_space(3))) unsigned int*       lptr_t;
__device__ __forceinline__ void gl_lds16(const void* g, void* l) {
  __builtin_amdgcn_global_load_lds((gptr_t)g, (lptr_t)l, 16, 0, 0);
}

// ---------- kernel 1: convert [x | h] -> bf16 merged (1024 x 4096) ----------
__global__ __launch_bounds__(256) void k_convert_merged(
    const float* __restrict__ x, const float* __restrict__ h,
    unsigned short* __restrict__ merged) {
  int tid = blockIdx.x * 256 + threadIdx.x;   // 0 .. 524287
  int e0  = tid * 8;                          // element offset in merged
  int b   = e0 >> 12;                         // / 4096
  int col = e0 & 4095;
  const float* src = (col < D_) ? (x + (size_t)b * D_ + col)
                                : (h + (size_t)b * H_ + (col - D_));
  f32x4 v0 = *(const f32x4*)src;
  f32x4 v1 = *(const f32x4*)(src + 4);
  u16x8 o;
  o[0] = f2bf_rne(v0[0]); o[1] = f2bf_rne(v0[1]);
  o[2] = f2bf_rne(v0[2]); o[3] = f2bf_rne(v0[3]);
  o[4] = f2bf_rne(v1[0]); o[5] = f2bf_rne(v1[1]);
  o[6] = f2bf_rne(v1[2]); o[7] = f2bf_rne(v1[3]);
  *(u16x8*)(merged + e0) = o;
}

// ---------- kernel 2: W (4096 x 8192 f32, KxN) -> Wt (8192 x 4096 bf16, NxK) --
// 64x64 f32 tile in LDS, XOR-swizzled (byte ^= ((k>>3)&7)<<4) on BOTH the
// ds_write_b128 stage and the per-lane b32 transposed reads (rule #21).
// Write phase: even 32-bank coverage. Read phase: lane reads n fixed, k
// varying; XOR spreads the fixed bank n%32 by (lane&7)*4 -> exact 2-way = free.
__global__ __launch_bounds__(256) void k_transpose_w(
    const float* __restrict__ W, unsigned short* __restrict__ Wt) {
  __shared__ float lt[64 * 64];
  char* lbase = (char*)lt;
  const int t  = threadIdx.x;
  const int n0 = blockIdx.x * 64;             // 8192/64 = 128
  const int k0 = blockIdx.y * 64;             // 4096/64 = 64
#pragma unroll
  for (int i = 0; i < 4; ++i) {
    int kk = (t >> 4) + i * 16;               // 0..63
    int nn = (t & 15) * 4;                    // 0..60
    f32x4 v = *(const f32x4*)&W[(size_t)(k0 + kk) * N_ + n0 + nn];
    int by = (kk * 256 + nn * 4) ^ (((kk >> 3) & 7) << 4);
    *(f32x4*)(lbase + by) = v;
  }
  __syncthreads();
#pragma unroll
  for (int i = 0; i < 2; ++i) {
    int n  = (t >> 3) + i * 32;               // 0..63
    int kc = (t & 7) * 8;                     // 0..56, k>>3 == t&7 for all j
    u16x8 o;
#pragma unroll
    for (int j = 0; j < 8; ++j) {
      int k  = kc + j;
      int by = (k * 256 + n * 4) ^ (((k >> 3) & 7) << 4);
      o[j] = f2bf_rne(*(const float*)(lbase + by));
    }
    *(u16x8*)&Wt[(size_t)(n0 + n) * K_ + k0 + kc] = o;
  }
}

// ---------- kernel 3: GEMM  C(1024x8192 f32) = merged(1024x4096) * Wt^T ------
// m97 structure: 128x128 tile, BK=64, 4 waves (2x2), 16x16x32 bf16 MFMA,
// global_load_lds width=16 staging, linear LDS. (unchanged from round 2)
#define TM 128
#define TN 128
#define TK 64

__global__ __launch_bounds__(256) void k_gemm(
    const unsigned short* __restrict__ A,   // M x K bf16 row-major
    const unsigned short* __restrict__ Bt,  // N x K bf16 row-major
    float* __restrict__ C) {                // M x N f32
  __shared__ unsigned short As[TM * TK];    // [128][64], row stride 128 B
  __shared__ unsigned short Bs[TN * TK];
  const int t    = threadIdx.x;
  const int bx   = blockIdx.x;              // N tile: 0..63
  const int by   = blockIdx.y;              // M tile: 0..7
  const int wid  = t >> 6;
  const int lane = t & 63;
  const int wr   = wid >> 1, wc = wid & 1;  // 2x2 waves, 64x64 each
  const int ln15 = lane & 15, kq = lane >> 4;

  const int srow  = t >> 3;                 // 0..31 per sweep
  const int scolb = (t & 7) * 16;           // byte col within 128-B row

  const char* gA = (const char*)A + (size_t)(by * TM + srow) * (K_ * 2) + scolb;
  const char* gB = (const char*)Bt + (size_t)(bx * TN + srow) * (K_ * 2) + scolb;
  char* lA = (char*)As + srow * (TK * 2) + scolb;
  char* lB = (char*)Bs + srow * (TK * 2) + scolb;

  f32x4 acc[4][4] = {};

  for (int kt = 0; kt < K_ / TK; ++kt) {
    const int gofs = kt * (TK * 2);         // byte offset along K
#pragma unroll
    for (int i = 0; i < 4; ++i) {           // 32 rows per sweep
      gl_lds16(gA + (size_t)(i * 32) * (K_ * 2) + gofs, lA + i * 32 * (TK * 2));
      gl_lds16(gB + (size_t)(i * 32) * (K_ * 2) + gofs, lB + i * 32 * (TK * 2));
    }
    __syncthreads();                        // compiler drains vmcnt before barrier
#pragma unroll
    for (int ks = 0; ks < 2; ++ks) {        // two K=32 sub-steps
      bf16x8 a[4], b[4];
#pragma unroll
      for (int mi = 0; mi < 4; ++mi)
        a[mi] = *(const bf16x8*)((const char*)As +
                 (wr * 64 + mi * 16 + ln15) * (TK * 2) + ks * 64 + kq * 16);
#pragma unroll
      for (int ni = 0; ni < 4; ++ni)
        b[ni] = *(const bf16x8*)((const char*)Bs +
                 (wc * 64 + ni * 16 + ln15) * (TK * 2) + ks * 64 + kq * 16);
#pragma unroll
      for (int mi = 0; mi < 4; ++mi)
#pragma unroll
        for (int ni = 0; ni < 4; ++ni)
          acc[mi][ni] = __builtin_amdgcn_mfma_f32_16x16x32_bf16(
              a[mi], b[ni], acc[mi][ni], 0, 0, 0);
    }
    __syncthreads();
  }

  // epilogue: C/D layout col = lane&15, row = (lane>>4)*4 + reg  [m89/m91]
  const int crow0 = by * TM + wr * 64 + kq * 4;
  const int ccol0 = bx * TN + wc * 64 + ln15;
#pragma unroll
  for (int mi = 0; mi < 4; ++mi)
#pragma unroll
    for (int ni = 0; ni < 4; ++ni)
#pragma unroll
      for (int r = 0; r < 4; ++r)
        C[(size_t)(crow0 + mi * 16 + r) * N_ + ccol0 + ni * 16] = acc[mi][ni][r];
}

// ---------- kernel 4: LSTM gates ----------
__global__ __launch_bounds__(256) void k_gates(
    const float* __restrict__ wsum, const float* __restrict__ c,
    float* __restrict__ out) {
  int tid = blockIdx.x * 256 + threadIdx.x;  // 0 .. 524287
  int b   = tid >> 9;                        // / 512 float4-per-row
  int j   = (tid & 511) * 4;
  const float* base = wsum + (size_t)b * N_;
  f32x4 f  = *(const f32x4*)(base + j);
  f32x4 ii = *(const f32x4*)(base + H_ + j);
  f32x4 g  = *(const f32x4*)(base + 2 * H_ + j);
  f32x4 o  = *(const f32x4*)(base + 3 * H_ + j);
  f32x4 cc = *(const f32x4*)&c[(size_t)b * H_ + j];
  f32x4 r;
#pragma unroll
  for (int q = 0; q < 4; ++q) {
    float cn = cc[q] * sigf(f[q]) + sigf(ii[q]) * tanhf_(g[q]);
    r[q] = sigf(o[q]) * tanhf_(cn);
  }
  *(f32x4*)&out[(size_t)b * H_ + j] = r;
}

// ---------- launch ----------
extern "C" void kernel_launch(void* const* d_in, const int* in_sizes, int n_in,
                              void* d_out, int out_size, void* d_ws, size_t ws_size,
                              hipStream_t stream) {
  (void)in_sizes; (void)n_in; (void)out_size; (void)ws_size;
  const float* x = (const float*)d_in[0];
  const float* h = (const float*)d_in[1];
  const float* c = (const float*)d_in[2];
  const float* W = (const float*)d_in[3];
  float* out = (float*)d_out;

  char* ws = (char*)d_ws;
  unsigned short* merged = (unsigned short*)ws;                              // 8 MB
  unsigned short* Wt     = (unsigned short*)(ws + (size_t)8  * 1024 * 1024); // 64 MB
  float*          wsum   = (float*)(ws + (size_t)72 * 1024 * 1024);          // 32 MB

  k_convert_merged<<<2048, 256, 0, stream>>>(x, h, merged);
  k_transpose_w<<<dim3(128, 64), 256, 0, stream>>>(W, Wt);
  k_gemm<<<dim3(N_ / TN, B_ / TM), 256, 0, stream>>>(merged, Wt, wsum);
  k_gates<<<2048, 256, 0, stream>>>(wsum, c, out);
}